// Round 4
// baseline (2795.808 us; speedup 1.0000x reference)
//
#include <hip/hip_runtime.h>
#include <stdint.h>

#define BB 4
#define NN 16384
#define NPOINT 1024
#define NSAMPLE 32
#define CC 64
#define RADIUS2 0.00999999977648258209228515625f
#define BIGF 1.0e10f

#define FT 1024  // fps threads per block (16 waves)

typedef float f32x2 __attribute__((ext_vector_type(2)));

__device__ __forceinline__ f32x2 pk_add(f32x2 a, f32x2 b) {
    f32x2 d;
    asm("v_pk_add_f32 %0, %1, %2" : "=v"(d) : "v"(a), "v"(b));
    return d;
}
__device__ __forceinline__ f32x2 pk_mul(f32x2 a, f32x2 b) {
    f32x2 d;
    asm("v_pk_mul_f32 %0, %1, %2" : "=v"(d) : "v"(a), "v"(b));
    return d;
}

// ---------------- repack w1 (64x67) -> (64x68) padded, pad=0 ----------------
__global__ __launch_bounds__(256) void repack_w1(const float* __restrict__ w1,
                                                 float* __restrict__ w1p) {
    int t = threadIdx.x;
    for (int i = t; i < 64 * 68; i += 256) {
        int o = i / 68, c = i % 68;
        w1p[i] = (c < 67) ? w1[o * 67 + c] : 0.0f;
    }
}

// DPP-based argmax step (max value, min index on ties) — validated bit-exact.
template <int CTRL>
__device__ __forceinline__ void amax_step(float& v, int& i) {
    int nv = __builtin_amdgcn_update_dpp(__float_as_int(v), __float_as_int(v),
                                         CTRL, 0xf, 0xf, false);
    int ni = __builtin_amdgcn_update_dpp(i, i, CTRL, 0xf, 0xf, false);
    float fv = __int_as_float(nv);
    if (fv > v || (fv == v && ni < i)) { v = fv; i = ni; }
}
__device__ __forceinline__ void wave_amax(float& v, int& i) {
    amax_step<0x111>(v, i);  // row_shr:1
    amax_step<0x112>(v, i);  // row_shr:2
    amax_step<0x114>(v, i);  // row_shr:4
    amax_step<0x118>(v, i);  // row_shr:8
    amax_step<0x142>(v, i);  // row_bcast:15
    amax_step<0x143>(v, i);  // row_bcast:31  -> lane63 holds full wave result
}

#define PAIR_LIST(X) X(0) X(1) X(2) X(3) X(4) X(5) X(6) X(7)

// ---------------- FPS: one 1024-thread block per batch ----------------
__global__ __launch_bounds__(FT)
__attribute__((amdgpu_waves_per_eu(4, 4)))
void fps_kernel(const float* __restrict__ xyz, float* __restrict__ new_xyz) {
    const int b = blockIdx.x;
    const int t = threadIdx.x;
    const int lane = t & 63;
    const int w = t >> 6;  // 0..15

    __shared__ float2 svi[2][16];  // parity double-buffered per-wave (v, idx)

    const float* xb = xyz + (size_t)b * NN * 3;

    // named scalar pairs -> guaranteed VGPR residency (R2/R3: arrays went to
    // scratch, VGPR_Count=84, kernel was L2-stream-bound at 1.8us/iter)
#define DECL(k) f32x2 px##k, py##k, pz##k, dd##k;
    PAIR_LIST(DECL)
#undef DECL

    // load 2 consecutive points per pair slot: g = 2*(k*FT + t) and g+1.
    // 24B per pair, 8B-aligned -> three dwordx2 loads, repack in registers.
#define LOAD(k) {                                                   \
        const float* p = xb + (size_t)6 * (k * FT + t);             \
        f32x2 a = *(const f32x2*)(p + 0);                           \
        f32x2 bq = *(const f32x2*)(p + 2);                          \
        f32x2 c = *(const f32x2*)(p + 4);                           \
        px##k.x = a.x;  py##k.x = a.y;  pz##k.x = bq.x;             \
        px##k.y = bq.y; py##k.y = c.x;  pz##k.y = c.y;              \
        dd##k.x = BIGF; dd##k.y = BIGF;                             \
    }
    PAIR_LIST(LOAD)
#undef LOAD

    // initial centroid = point 0
    float cx = xb[0], cy = xb[1], cz = xb[2];

    for (int i = 0; i < NPOINT; ++i) {
        if (t == 0) {
            float* o = new_xyz + ((size_t)b * NPOINT + i) * 3;
            o[0] = cx; o[1] = cy; o[2] = cz;
        }
        f32x2 ncx, ncy, ncz;
        ncx.x = -cx; ncx.y = -cx;
        ncy.x = -cy; ncy.y = -cy;
        ncz.x = -cz; ncz.y = -cz;

        float bv = -1.0f;
        int bj = 0;
        // EXACT numpy semantics per element: sub = a+(-b); products rounded
        // individually; sum order (x^2+y^2)+z^2; min; running max with strict
        // > and ascending local slot -> first-occurrence tie-break.
#define STEP(k) {                                                   \
        f32x2 dx = pk_add(px##k, ncx);                              \
        f32x2 dy = pk_add(py##k, ncy);                              \
        f32x2 dz = pk_add(pz##k, ncz);                              \
        f32x2 m0 = pk_mul(dx, dx);                                  \
        f32x2 m1 = pk_mul(dy, dy);                                  \
        f32x2 m2 = pk_mul(dz, dz);                                  \
        f32x2 d  = pk_add(pk_add(m0, m1), m2);                      \
        dd##k.x = fminf(dd##k.x, d.x);                              \
        dd##k.y = fminf(dd##k.y, d.y);                              \
        if (dd##k.x > bv) { bv = dd##k.x; bj = 2 * k; }             \
        if (dd##k.y > bv) { bv = dd##k.y; bj = 2 * k + 1; }         \
    }
        PAIR_LIST(STEP)
#undef STEP
        // global index: g = (bj>>1)*2*FT + 2*t + (bj&1); monotone in bj for
        // fixed t -> in-thread first-occurrence holds
        int bi = (bj >> 1) * (2 * FT) + 2 * t + (bj & 1);

        wave_amax(bv, bi);
        if (lane == 63) svi[i & 1][w] = make_float2(bv, __int_as_float(bi));
        __syncthreads();

        // each lane reads ONE slot (16 slots, 4-lane broadcast groups), then
        // a second wave reduce; duplicates are harmless for (max, min-idx)
        float2 s = svi[i & 1][lane & 15];
        float v2 = s.x;
        int i2 = __float_as_int(s.y);
        wave_amax(v2, i2);
        int ixs = __builtin_amdgcn_readlane(i2, 63);  // uniform -> SGPR

        // scalar-path load of next centroid
        cx = xb[ixs * 3 + 0];
        cy = xb[ixs * 3 + 1];
        cz = xb[ixs * 3 + 2];
    }
}

// ---------------- ball query: one wave per centroid ----------------
__global__ __launch_bounds__(256) void ballquery_kernel(const float* __restrict__ xyz,
                                                        const float* __restrict__ new_xyz,
                                                        int* __restrict__ nidx) {
    const int t = threadIdx.x;
    const int lane = t & 63;
    const int w = t >> 6;
    const int cid = blockIdx.x * 4 + w;  // 0..4095
    const int b = cid >> 10;

    __shared__ int list[4][NSAMPLE];

    const float* xb = xyz + (size_t)b * NN * 3;
    const float* c = new_xyz + (size_t)cid * 3;
    float cx = c[0], cy = c[1], cz = c[2];

    int cnt = 0;
    for (int base = 0; base < NN && cnt < NSAMPLE; base += 64) {
        int j = base + lane;
        float dx = __fsub_rn(xb[j * 3 + 0], cx);
        float dy = __fsub_rn(xb[j * 3 + 1], cy);
        float dz = __fsub_rn(xb[j * 3 + 2], cz);
        float d2 = __fadd_rn(__fadd_rn(__fmul_rn(dx, dx), __fmul_rn(dy, dy)),
                             __fmul_rn(dz, dz));
        bool hit = d2 < RADIUS2;
        unsigned long long m = __ballot(hit);
        int pre = __popcll(m & ((1ull << lane) - 1ull));
        if (hit) {
            int pos = cnt + pre;
            if (pos < NSAMPLE) list[w][pos] = j;
        }
        cnt += __popcll(m);  // ballot result uniform -> cnt stays wave-uniform
    }
    __syncthreads();
    if (lane < NSAMPLE) {
        int first = list[w][0];  // >=1 hit always: centroid is a member point
        int v = (lane < cnt) ? list[w][lane] : first;
        nidx[(size_t)cid * NSAMPLE + lane] = v;
    }
}

// ---------------- grouped MLP + maxpool: one thread per (point,sample) ------
__global__ __launch_bounds__(256, 2) void mlp_kernel(
    const float* __restrict__ xyz, const float* __restrict__ features,
    const float* __restrict__ new_xyz, const int* __restrict__ nidx,
    const float* __restrict__ w1p, const float* __restrict__ b1,
    const float* __restrict__ w2, const float* __restrict__ b2,
    const float* __restrict__ w3, const float* __restrict__ b3,
    float* __restrict__ out) {
    const int gid = blockIdx.x * 256 + threadIdx.x;
    const int s = gid & 31;
    const int pg = gid >> 5;  // b*1024 + p
    const int b = pg >> 10;
    const int p = pg & 1023;

    const int idx = nidx[gid];
    const float* nc = new_xyz + (size_t)pg * 3;
    const float* pt = xyz + ((size_t)b * NN + idx) * 3;
    float gx = pt[0] - nc[0], gy = pt[1] - nc[1], gz = pt[2] - nc[2];

    float fin[64];
    const float4* fp = (const float4*)(features + ((size_t)b * NN + idx) * CC);
#pragma unroll
    for (int j = 0; j < 16; ++j) {
        float4 q = fp[j];
        fin[4 * j] = q.x; fin[4 * j + 1] = q.y;
        fin[4 * j + 2] = q.z; fin[4 * j + 3] = q.w;
    }

    float h1[64];
#pragma unroll
    for (int o = 0; o < 64; ++o) {
        const float4* wr = (const float4*)(w1p + o * 68);  // uniform -> s_load
        float acc = b1[o];
        float4 q0 = wr[0];
        acc = fmaf(q0.x, gx, acc);
        acc = fmaf(q0.y, gy, acc);
        acc = fmaf(q0.z, gz, acc);
        acc = fmaf(q0.w, fin[0], acc);
#pragma unroll
        for (int j = 1; j < 17; ++j) {
            float4 q = wr[j];
            int c0 = 4 * j - 3;
            acc = fmaf(q.x, fin[c0], acc);
            acc = fmaf(q.y, fin[c0 + 1], acc);
            acc = fmaf(q.z, fin[c0 + 2], acc);
            if (c0 + 3 < 64) acc = fmaf(q.w, fin[c0 + 3], acc);
        }
        h1[o] = fmaxf(acc, 0.0f);
    }

    float h2[64];
#pragma unroll
    for (int o = 0; o < 64; ++o) {
        const float4* wr = (const float4*)(w2 + o * 64);
        float acc = b2[o];
#pragma unroll
        for (int j = 0; j < 16; ++j) {
            float4 q = wr[j];
            acc = fmaf(q.x, h1[4 * j], acc);
            acc = fmaf(q.y, h1[4 * j + 1], acc);
            acc = fmaf(q.z, h1[4 * j + 2], acc);
            acc = fmaf(q.w, h1[4 * j + 3], acc);
        }
        h2[o] = fmaxf(acc, 0.0f);
    }

    float* ob = out + (size_t)b * 128 * NPOINT + p;
#pragma unroll
    for (int o = 0; o < 128; ++o) {
        const float4* wr = (const float4*)(w3 + o * 64);
        float acc = b3[o];
#pragma unroll
        for (int j = 0; j < 16; ++j) {
            float4 q = wr[j];
            acc = fmaf(q.x, h2[4 * j], acc);
            acc = fmaf(q.y, h2[4 * j + 1], acc);
            acc = fmaf(q.z, h2[4 * j + 2], acc);
            acc = fmaf(q.w, h2[4 * j + 3], acc);
        }
        float r = fmaxf(acc, 0.0f);
#pragma unroll
        for (int off = 1; off < 32; off <<= 1) {
            float orr = __shfl_xor(r, off);
            r = fmaxf(r, orr);
        }
        if (s == 0) ob[(size_t)o * NPOINT] = r;
    }
}

extern "C" void kernel_launch(void* const* d_in, const int* in_sizes, int n_in,
                              void* d_out, int out_size, void* d_ws, size_t ws_size,
                              hipStream_t stream) {
    const float* xyz = (const float*)d_in[0];
    const float* features = (const float*)d_in[1];
    const float* w1 = (const float*)d_in[2];
    const float* b1 = (const float*)d_in[3];
    const float* w2 = (const float*)d_in[4];
    const float* b2 = (const float*)d_in[5];
    const float* w3 = (const float*)d_in[6];
    const float* b3 = (const float*)d_in[7];

    float* out = (float*)d_out;
    float* new_xyz = out;                          // B*NPOINT*3
    float* new_feat = out + BB * NPOINT * 3;       // B*128*NPOINT

    int* nidx = (int*)d_ws;                        // B*NPOINT*NSAMPLE ints
    float* w1p = (float*)((char*)d_ws + (size_t)BB * NPOINT * NSAMPLE * sizeof(int));

    hipLaunchKernelGGL(repack_w1, dim3(1), dim3(256), 0, stream, w1, w1p);
    hipLaunchKernelGGL(fps_kernel, dim3(BB), dim3(FT), 0, stream, xyz, new_xyz);
    hipLaunchKernelGGL(ballquery_kernel, dim3(BB * NPOINT / 4), dim3(256), 0, stream,
                       xyz, new_xyz, nidx);
    hipLaunchKernelGGL(mlp_kernel, dim3(BB * NPOINT * NSAMPLE / 256), dim3(256), 0, stream,
                       xyz, features, new_xyz, nidx, w1p, b1, w2, b2, w3, b3, new_feat);
}

// Round 5
// 2553.044 us; speedup vs baseline: 1.0951x; 1.0951x over previous
//
#include <hip/hip_runtime.h>
#include <stdint.h>

#define BB 4
#define NN 16384
#define NPOINT 1024
#define NSAMPLE 32
#define CC 64
#define RADIUS2 0.00999999977648258209228515625f
#define BIGF 1.0e10f

#define FT 512   // fps threads per block (8 waves)

typedef float f32x2 __attribute__((ext_vector_type(2)));

__device__ __forceinline__ f32x2 pk_add(f32x2 a, f32x2 b) {
    f32x2 d;
    asm("v_pk_add_f32 %0, %1, %2" : "=v"(d) : "v"(a), "v"(b));
    return d;
}
__device__ __forceinline__ f32x2 pk_mul(f32x2 a, f32x2 b) {
    f32x2 d;
    asm("v_pk_mul_f32 %0, %1, %2" : "=v"(d) : "v"(a), "v"(b));
    return d;
}

// ---------------- repack w1 (64x67) -> (64x68) padded, pad=0 ----------------
__global__ __launch_bounds__(256) void repack_w1(const float* __restrict__ w1,
                                                 float* __restrict__ w1p) {
    int t = threadIdx.x;
    for (int i = t; i < 64 * 68; i += 256) {
        int o = i / 68, c = i % 68;
        w1p[i] = (c < 67) ? w1[o * 67 + c] : 0.0f;
    }
}

// DPP-based argmax step (max value, min index on ties) — validated bit-exact.
template <int CTRL>
__device__ __forceinline__ void amax_step(float& v, int& i) {
    int nv = __builtin_amdgcn_update_dpp(__float_as_int(v), __float_as_int(v),
                                         CTRL, 0xf, 0xf, false);
    int ni = __builtin_amdgcn_update_dpp(i, i, CTRL, 0xf, 0xf, false);
    float fv = __int_as_float(nv);
    if (fv > v || (fv == v && ni < i)) { v = fv; i = ni; }
}
__device__ __forceinline__ void wave_amax(float& v, int& i) {
    amax_step<0x111>(v, i);  // row_shr:1
    amax_step<0x112>(v, i);  // row_shr:2
    amax_step<0x114>(v, i);  // row_shr:4
    amax_step<0x118>(v, i);  // row_shr:8
    amax_step<0x142>(v, i);  // row_bcast:15
    amax_step<0x143>(v, i);  // row_bcast:31  -> lane63 holds full wave result
}

#define PAIR_LIST(X) \
    X(0) X(1) X(2) X(3) X(4) X(5) X(6) X(7) \
    X(8) X(9) X(10) X(11) X(12) X(13) X(14) X(15)

// ---------------- FPS: one 512-thread block per batch ----------------
// NOTE: deliberately NO __restrict__ on xyz/new_xyz. With restrict, the
// coord loads are invariant loads and LLVM "spills" them by REMATERIALIZING
// (re-loading from memory every iteration) -- R1..R4 all showed VGPR_Count
// 48..84 and ~2.2us/iter of L1/L2 re-streaming. The in-loop store to
// new_xyz may alias xyz without restrict, making the reload illegal, so
// the values must stay register-resident.
__global__ __launch_bounds__(FT, 2)
void fps_kernel(const float* xyz, float* new_xyz) {
    const int b = blockIdx.x;
    const int t = threadIdx.x;
    const int lane = t & 63;
    const int w = t >> 6;  // 0..7

    __shared__ float2 svi[2][8];  // parity double-buffered per-wave (v, idx)

    const float* xb = xyz + (size_t)b * NN * 3;

#define DECL(k) f32x2 px##k, py##k, pz##k, dd##k;
    PAIR_LIST(DECL)
#undef DECL

    // load 2 consecutive points per pair slot: g = 2*(k*FT + t) and g+1.
#define LOAD(k) {                                                   \
        const float* p = xb + (size_t)6 * (k * FT + t);             \
        f32x2 a = *(const f32x2*)(p + 0);                           \
        f32x2 bq = *(const f32x2*)(p + 2);                          \
        f32x2 c = *(const f32x2*)(p + 4);                           \
        px##k.x = a.x;  py##k.x = a.y;  pz##k.x = bq.x;             \
        px##k.y = bq.y; py##k.y = c.x;  pz##k.y = c.y;              \
        dd##k.x = BIGF; dd##k.y = BIGF;                             \
    }
    PAIR_LIST(LOAD)
#undef LOAD

    // initial centroid = point 0
    float cx = xb[0], cy = xb[1], cz = xb[2];

    for (int i = 0; i < NPOINT; ++i) {
        if (t == 0) {
            float* o = new_xyz + ((size_t)b * NPOINT + i) * 3;
            o[0] = cx; o[1] = cy; o[2] = cz;
        }
        f32x2 ncx, ncy, ncz;
        ncx.x = -cx; ncx.y = -cx;
        ncy.x = -cy; ncy.y = -cy;
        ncz.x = -cz; ncz.y = -cz;

        float bv = -1.0f;
        int bj = 0;
        // EXACT numpy semantics per element: sub = a+(-b); products rounded
        // individually; sum order (x^2+y^2)+z^2; min; running max with strict
        // > and ascending local slot -> first-occurrence tie-break.
#define STEP(k) {                                                   \
        f32x2 dx = pk_add(px##k, ncx);                              \
        f32x2 dy = pk_add(py##k, ncy);                              \
        f32x2 dz = pk_add(pz##k, ncz);                              \
        f32x2 m0 = pk_mul(dx, dx);                                  \
        f32x2 m1 = pk_mul(dy, dy);                                  \
        f32x2 m2 = pk_mul(dz, dz);                                  \
        f32x2 d  = pk_add(pk_add(m0, m1), m2);                      \
        dd##k.x = fminf(dd##k.x, d.x);                              \
        dd##k.y = fminf(dd##k.y, d.y);                              \
        if (dd##k.x > bv) { bv = dd##k.x; bj = 2 * k; }             \
        if (dd##k.y > bv) { bv = dd##k.y; bj = 2 * k + 1; }         \
    }
        PAIR_LIST(STEP)
#undef STEP
        // global index: g = (bj>>1)*2*FT + 2*t + (bj&1); monotone in bj for
        // fixed t -> in-thread first-occurrence holds
        int bi = (bj >> 1) * (2 * FT) + 2 * t + (bj & 1);

        wave_amax(bv, bi);
        if (lane == 63) svi[i & 1][w] = make_float2(bv, __int_as_float(bi));
        __syncthreads();

        // each lane reads ONE of the 8 wave slots (broadcast groups), then a
        // second wave reduce; duplicates are harmless for (max, min-idx)
        float2 s = svi[i & 1][lane & 7];
        float v2 = s.x;
        int i2 = __float_as_int(s.y);
        wave_amax(v2, i2);
        int ixs = __builtin_amdgcn_readlane(i2, 63);  // uniform -> SGPR

        // scalar-path load of next centroid
        cx = xb[ixs * 3 + 0];
        cy = xb[ixs * 3 + 1];
        cz = xb[ixs * 3 + 2];
    }
}

// ---------------- ball query: one wave per centroid ----------------
__global__ __launch_bounds__(256) void ballquery_kernel(const float* __restrict__ xyz,
                                                        const float* __restrict__ new_xyz,
                                                        int* __restrict__ nidx) {
    const int t = threadIdx.x;
    const int lane = t & 63;
    const int w = t >> 6;
    const int cid = blockIdx.x * 4 + w;  // 0..4095
    const int b = cid >> 10;

    __shared__ int list[4][NSAMPLE];

    const float* xb = xyz + (size_t)b * NN * 3;
    const float* c = new_xyz + (size_t)cid * 3;
    float cx = c[0], cy = c[1], cz = c[2];

    int cnt = 0;
    for (int base = 0; base < NN && cnt < NSAMPLE; base += 64) {
        int j = base + lane;
        float dx = __fsub_rn(xb[j * 3 + 0], cx);
        float dy = __fsub_rn(xb[j * 3 + 1], cy);
        float dz = __fsub_rn(xb[j * 3 + 2], cz);
        float d2 = __fadd_rn(__fadd_rn(__fmul_rn(dx, dx), __fmul_rn(dy, dy)),
                             __fmul_rn(dz, dz));
        bool hit = d2 < RADIUS2;
        unsigned long long m = __ballot(hit);
        int pre = __popcll(m & ((1ull << lane) - 1ull));
        if (hit) {
            int pos = cnt + pre;
            if (pos < NSAMPLE) list[w][pos] = j;
        }
        cnt += __popcll(m);  // ballot result uniform -> cnt stays wave-uniform
    }
    __syncthreads();
    if (lane < NSAMPLE) {
        int first = list[w][0];  // >=1 hit always: centroid is a member point
        int v = (lane < cnt) ? list[w][lane] : first;
        nidx[(size_t)cid * NSAMPLE + lane] = v;
    }
}

// ---------------- grouped MLP + maxpool: one thread per (point,sample) ------
__global__ __launch_bounds__(256, 2) void mlp_kernel(
    const float* __restrict__ xyz, const float* __restrict__ features,
    const float* __restrict__ new_xyz, const int* __restrict__ nidx,
    const float* __restrict__ w1p, const float* __restrict__ b1,
    const float* __restrict__ w2, const float* __restrict__ b2,
    const float* __restrict__ w3, const float* __restrict__ b3,
    float* __restrict__ out) {
    const int gid = blockIdx.x * 256 + threadIdx.x;
    const int s = gid & 31;
    const int pg = gid >> 5;  // b*1024 + p
    const int b = pg >> 10;
    const int p = pg & 1023;

    const int idx = nidx[gid];
    const float* nc = new_xyz + (size_t)pg * 3;
    const float* pt = xyz + ((size_t)b * NN + idx) * 3;
    float gx = pt[0] - nc[0], gy = pt[1] - nc[1], gz = pt[2] - nc[2];

    float fin[64];
    const float4* fp = (const float4*)(features + ((size_t)b * NN + idx) * CC);
#pragma unroll
    for (int j = 0; j < 16; ++j) {
        float4 q = fp[j];
        fin[4 * j] = q.x; fin[4 * j + 1] = q.y;
        fin[4 * j + 2] = q.z; fin[4 * j + 3] = q.w;
    }

    float h1[64];
#pragma unroll
    for (int o = 0; o < 64; ++o) {
        const float4* wr = (const float4*)(w1p + o * 68);  // uniform -> s_load
        float acc = b1[o];
        float4 q0 = wr[0];
        acc = fmaf(q0.x, gx, acc);
        acc = fmaf(q0.y, gy, acc);
        acc = fmaf(q0.z, gz, acc);
        acc = fmaf(q0.w, fin[0], acc);
#pragma unroll
        for (int j = 1; j < 17; ++j) {
            float4 q = wr[j];
            int c0 = 4 * j - 3;
            acc = fmaf(q.x, fin[c0], acc);
            acc = fmaf(q.y, fin[c0 + 1], acc);
            acc = fmaf(q.z, fin[c0 + 2], acc);
            if (c0 + 3 < 64) acc = fmaf(q.w, fin[c0 + 3], acc);
        }
        h1[o] = fmaxf(acc, 0.0f);
    }

    float h2[64];
#pragma unroll
    for (int o = 0; o < 64; ++o) {
        const float4* wr = (const float4*)(w2 + o * 64);
        float acc = b2[o];
#pragma unroll
        for (int j = 0; j < 16; ++j) {
            float4 q = wr[j];
            acc = fmaf(q.x, h1[4 * j], acc);
            acc = fmaf(q.y, h1[4 * j + 1], acc);
            acc = fmaf(q.z, h1[4 * j + 2], acc);
            acc = fmaf(q.w, h1[4 * j + 3], acc);
        }
        h2[o] = fmaxf(acc, 0.0f);
    }

    float* ob = out + (size_t)b * 128 * NPOINT + p;
#pragma unroll
    for (int o = 0; o < 128; ++o) {
        const float4* wr = (const float4*)(w3 + o * 64);
        float acc = b3[o];
#pragma unroll
        for (int j = 0; j < 16; ++j) {
            float4 q = wr[j];
            acc = fmaf(q.x, h2[4 * j], acc);
            acc = fmaf(q.y, h2[4 * j + 1], acc);
            acc = fmaf(q.z, h2[4 * j + 2], acc);
            acc = fmaf(q.w, h2[4 * j + 3], acc);
        }
        float r = fmaxf(acc, 0.0f);
#pragma unroll
        for (int off = 1; off < 32; off <<= 1) {
            float orr = __shfl_xor(r, off);
            r = fmaxf(r, orr);
        }
        if (s == 0) ob[(size_t)o * NPOINT] = r;
    }
}

extern "C" void kernel_launch(void* const* d_in, const int* in_sizes, int n_in,
                              void* d_out, int out_size, void* d_ws, size_t ws_size,
                              hipStream_t stream) {
    const float* xyz = (const float*)d_in[0];
    const float* features = (const float*)d_in[1];
    const float* w1 = (const float*)d_in[2];
    const float* b1 = (const float*)d_in[3];
    const float* w2 = (const float*)d_in[4];
    const float* b2 = (const float*)d_in[5];
    const float* w3 = (const float*)d_in[6];
    const float* b3 = (const float*)d_in[7];

    float* out = (float*)d_out;
    float* new_xyz = out;                          // B*NPOINT*3
    float* new_feat = out + BB * NPOINT * 3;       // B*128*NPOINT

    int* nidx = (int*)d_ws;                        // B*NPOINT*NSAMPLE ints
    float* w1p = (float*)((char*)d_ws + (size_t)BB * NPOINT * NSAMPLE * sizeof(int));

    hipLaunchKernelGGL(repack_w1, dim3(1), dim3(256), 0, stream, w1, w1p);
    hipLaunchKernelGGL(fps_kernel, dim3(BB), dim3(FT), 0, stream, xyz, new_xyz);
    hipLaunchKernelGGL(ballquery_kernel, dim3(BB * NPOINT / 4), dim3(256), 0, stream,
                       xyz, new_xyz, nidx);
    hipLaunchKernelGGL(mlp_kernel, dim3(BB * NPOINT * NSAMPLE / 256), dim3(256), 0, stream,
                       xyz, features, new_xyz, nidx, w1p, b1, w2, b2, w3, b3, new_feat);
}